// Round 10
// baseline (720.890 us; speedup 1.0000x reference)
//
#include <hip/hip_runtime.h>

#define Bdim 8
#define Cdim 64
#define Ndim 4096
#define Kdim 32
#define ROWS (Bdim*Ndim)   /* 32768 */
#define BN_EPS 1e-5f

typedef __attribute__((ext_vector_type(8))) short s8v;
typedef __attribute__((ext_vector_type(4))) float f4v;

__device__ __forceinline__ float dot4(float4 a, float4 b){
  return a.x*b.x + a.y*b.y + a.z*b.z + a.w*b.w;
}
__device__ __forceinline__ int wofs(int o, int g){ return o*64 + (((g ^ ((o>>2)&7)))<<2); }
__device__ __forceinline__ unsigned keyOf(float f){
  unsigned u = __float_as_uint(f);
  return (u & 0x80000000u) ? ~u : (u ^ 0x80000000u);
}
// RNE float->bf16 (bits) and back
__device__ __forceinline__ unsigned bfhi(float f){
  unsigned u = __float_as_uint(f);
  return (u + 0x7FFFu + ((u>>16)&1u)) >> 16;
}

// ---------------------------------------------------------------- prep+proj+pack fused
// x (B,C,N) -> transpose tile in LDS -> sq + Q/PK/PV projections + bf16 hi/lo
// pack of X in MFMA B-fragment layout P[b][mt][k8][n][j] (j=c%8 fastest).
__global__ __launch_bounds__(256) void prep_proj_kernel(const float* __restrict__ x,
    const float* __restrict__ wq, const float* __restrict__ wk,
    const float* __restrict__ wv,
    float* __restrict__ sq,
    float* __restrict__ Qo, float* __restrict__ PKo, float* __restrict__ PVo,
    float* __restrict__ accZ, short* __restrict__ Ph, short* __restrict__ Pl)
{
  __shared__ __align__(16) float ftile[64*68];
  __shared__ __align__(16) float Ws[3][64*64];
  const int tid = threadIdx.x;
  const int blk = blockIdx.x;
  const int b  = blk & 7;
  const int n0 = (blk >> 3) * 64;
  if (blk == 0) accZ[tid] = 0.f;   // 256 floats: bn1s, bn1q, bn2s, bn2q
  for (int k=0;k<16;++k){
    int idx = tid + (k<<8);
    int c = idx>>6, nn = idx&63;
    ftile[nn*68+c] = x[((size_t)b*64+c)*Ndim + n0 + nn];
  }
  {
    const float* wp[3] = {wq, wk, wv};
    for (int m=0;m<3;++m)
      for (int k=0;k<16;++k){
        int idx = tid + (k<<8);
        int o = idx>>6, c = idx&63;
        Ws[m][wofs(o, c>>2) + (c&3)] = wp[m][o*64 + c];
      }
  }
  __syncthreads();
  if (tid < 64){
    float a = 0.f;
    #pragma unroll
    for (int c=0;c<64;++c){ float v = ftile[tid*68+c]; a += v*v; }
    sq[b*Ndim + n0 + tid] = a;
  }
  // ---- bf16 hi/lo pack (B-fragment-major): P[(b*256+mt)*8+k8][n*8+j]
  {
    const int mtBase = n0 >> 4;
    #pragma unroll
    for (int s=0;s<2;++s){
      int slot = tid + (s<<8);
      int mt = slot>>7, k8 = (slot>>4)&7, nn2 = slot&15;
      const float* src = &ftile[(mt*16+nn2)*68 + (k8<<3)];
      s8v h8, l8;
      #pragma unroll
      for (int j2=0;j2<8;++j2){
        float f = src[j2];
        unsigned hr = bfhi(f);
        float fh = __uint_as_float(hr<<16);
        unsigned lr2 = bfhi(f - fh);
        h8[j2] = (short)hr; l8[j2] = (short)lr2;
      }
      size_t off = ((((size_t)b<<8) + (size_t)(mtBase + mt))<<10) + (k8<<7) + (nn2<<3);
      *(s8v*)(Ph + off) = h8;
      *(s8v*)(Pl + off) = l8;
    }
  }
  const int tr = tid>>4, to = tid&15;
  const size_t rowBase = (size_t)b*Ndim + n0;
  float* outp[3] = {Qo, PKo, PVo};
  for (int m=0;m<3;++m){
    float acc[4][4];
    #pragma unroll
    for (int r=0;r<4;++r){ acc[r][0]=0.f; acc[r][1]=0.f; acc[r][2]=0.f; acc[r][3]=0.f; }
    #pragma unroll 4
    for (int c4=0;c4<16;++c4){
      float4 f[4], w[4];
      #pragma unroll
      for (int r=0;r<4;++r)  f[r] = *(const float4*)&ftile[(4*tr+r)*68 + (c4<<2)];
      #pragma unroll
      for (int oo=0;oo<4;++oo) w[oo] = *(const float4*)&Ws[m][wofs(4*to+oo, c4)];
      #pragma unroll
      for (int r=0;r<4;++r)
        #pragma unroll
        for (int oo=0;oo<4;++oo)
          acc[r][oo] += dot4(f[r], w[oo]);
    }
    #pragma unroll
    for (int r=0;r<4;++r){
      float4 v; v.x=acc[r][0]; v.y=acc[r][1]; v.z=acc[r][2]; v.w=acc[r][3];
      *(float4*)&outp[m][(rowBase + 4*tr + r)*64 + 4*to] = v;
    }
  }
}

// ---------------------------------------------------------------- knn + attention + BN1 stats
// MFMA (bf16 hi/lo split, 3 products) computes APPROX distances -> candidate
// filter (>= 36th lane-max) -> EXACT fp32 rescore (identical fmaf chain to
// the previous all-VALU version -> bit-identical selection) -> bitonic top-32.
__global__ __launch_bounds__(512, 4) void knn_attn_kernel(
    const float* __restrict__ x,
    const float* __restrict__ sq,
    const float* __restrict__ Qm, const float* __restrict__ PKm, const float* __restrict__ PVm,
    const short* __restrict__ Ph, const short* __restrict__ Pl,
    float* __restrict__ t1, float* __restrict__ bn1s, float* __restrict__ bn1q)
{
  __shared__ __align__(16) unsigned char smem[77888];
  float*    chunkF = (float*)smem;                 // [8][2048] 64 KB (distance phase)
  int*      candI  = (int*)smem;                   // [8][64]  (alias, selection)
  int*      outIdx = (int*)(smem + 2048);          // [8][32]
  float*    enS    = (float*)(smem + 3072);        // [8][128]
  float*    red1   = (float*)(smem + 3072);        // [512] (alias enS after use)
  float*    red2   = (float*)(smem + 5120);        // [512]
  short*    qhiL   = (short*)(smem + 65536);       // [16][64] bf16 bits (rows 8-15 zero)
  short*    qloL   = (short*)(smem + 67584);       // [16][64]
  float*    fnS    = (float*)(smem + 69632);       // [8][64]
  float*    qvS    = (float*)(smem + 71680);       // [8][64]
  float*    pknS   = (float*)(smem + 73728);       // [8][64]
  float*    pvnS   = (float*)(smem + 75776);       // [8][64]
  float*    sqnS   = (float*)(smem + 77824);       // [8]

  const int tid = threadIdx.x;
  const int lane = tid & 63;
  const int w = tid >> 6;
  const int blk = blockIdx.x;
  const int b  = blk & 7;                          // XCD-locality swizzle
  const int n0 = (blk >> 3) << 3;                  // 8 queries
  const float* xb = x + (size_t)b*64*Ndim;

  {
    int j = tid>>6, c = tid&63;
    size_t ro = ((size_t)b*Ndim + n0 + j)*64 + c;
    float f = xb[(size_t)c*Ndim + n0 + j];
    fnS[tid]  = f;
    qvS[tid]  = Qm[ro];
    pknS[tid] = PKm[ro];
    pvnS[tid] = PVm[ro];
    if (tid < 8) sqnS[tid] = sq[b*Ndim + n0 + tid];
    unsigned hr = bfhi(f);
    float fh = __uint_as_float(hr<<16);
    unsigned lr2 = bfhi(f - fh);
    qhiL[tid] = (short)hr;  qloL[tid] = (short)lr2;
    qhiL[512 + tid] = 0;    qloL[512 + tid] = 0;   // zero-pad query rows 8..15
  }
  __syncthreads();

  const int qn = lane & 15, quad = lane >> 4;
  const s8v ah0 = *(const s8v*)&qhiL[qn*64 + quad*8];
  const s8v ah1 = *(const s8v*)&qhiL[qn*64 + 32 + quad*8];
  const s8v al0 = *(const s8v*)&qloL[qn*64 + quad*8];
  const s8v al1 = *(const s8v*)&qloL[qn*64 + 32 + quad*8];
  float sqn_r[4];
  #pragma unroll
  for (int r=0;r<4;++r) sqn_r[r] = sqnS[(quad&1)*4 + r];

  const short* Phb = Ph + ((size_t)b<<18);
  const short* Plb = Pl + ((size_t)b<<18);
  unsigned kk[64];

  for (int g=0; g<2; ++g){
    for (int t=0; t<16; ++t){
      const int mtL = (w<<4) + t;                 // 0..127 within group
      const int mtg = (g<<7) + mtL;               // global m-tile (16 m each)
      const size_t fo = ((size_t)mtg<<10) + (quad<<7) + (qn<<3);
      s8v bh0 = *(const s8v*)(Phb + fo);
      s8v bh1 = *(const s8v*)(Phb + fo + 512);
      s8v bl0 = *(const s8v*)(Plb + fo);
      s8v bl1 = *(const s8v*)(Plb + fo + 512);
      f4v D1 = {0.f,0.f,0.f,0.f}, D2 = {0.f,0.f,0.f,0.f};
      D1 = __builtin_amdgcn_mfma_f32_16x16x32_bf16(ah0, bh0, D1, 0,0,0);
      D1 = __builtin_amdgcn_mfma_f32_16x16x32_bf16(ah1, bh1, D1, 0,0,0);
      D2 = __builtin_amdgcn_mfma_f32_16x16x32_bf16(ah0, bl0, D2, 0,0,0);
      D2 = __builtin_amdgcn_mfma_f32_16x16x32_bf16(ah1, bl1, D2, 0,0,0);
      D2 = __builtin_amdgcn_mfma_f32_16x16x32_bf16(al0, bh0, D2, 0,0,0);
      D2 = __builtin_amdgcn_mfma_f32_16x16x32_bf16(al1, bh1, D2, 0,0,0);
      float sqm = sq[b*Ndim + (mtg<<4) + qn];
      if (quad < 2){
        int lm = (mtL<<4) + qn;
        #pragma unroll
        for (int r=0;r<4;++r){
          float d = 2.f*(D1[r]+D2[r]) - sqn_r[r] - sqm;
          chunkF[((quad<<2)+r)*2048 + lm] = d;
        }
      }
    }
    __syncthreads();
    #pragma unroll
    for (int i=0;i<32;++i)
      kk[(g<<5)+i] = keyOf(chunkF[(w<<11) + (i<<6) + lane]);
    __syncthreads();
  }

  // safety prefill (valid indices even if logic leaves slots unwritten)
  if (lane < 32) outIdx[(w<<5)+lane] = n0 + w;
  candI[(w<<6)+lane] = n0 + w;

  // ---- candidate filter on approx keys (threshold = 36th-largest lane-max)
  {
    unsigned lmax = kk[0];
    #pragma unroll
    for (int j=1;j<64;++j) lmax = lmax > kk[j] ? lmax : kk[j];
    unsigned T = 0u;
    #pragma unroll
    for (int bit=31; bit>=0; --bit){
      unsigned cand = T | (1u << bit);
      int cnt = (int)__popcll(__ballot(lmax >= cand));
      if (cnt >= 36) T = cand;
    }
    const unsigned long long below = (1ull << lane) - 1ull;
    int S = 0;
    #pragma unroll
    for (int j=0;j<64;++j){
      bool isc = (kk[j] >= T);
      unsigned long long mk = __ballot(isc);
      if (isc){
        int slot = S + (int)__popcll(mk & below);
        if (slot < 64) candI[(w<<6)+slot] = ((j>>5)<<11)+((j&31)<<6)+lane;
      }
      S += (int)__popcll(mk);
    }
    if (S > 64){
      // rare: gather approx top-64 instead (margin 64-32 ranks >> error)
      unsigned Te = 0u;
      for (int bit=31; bit>=0; --bit){
        unsigned cand = Te | (1u << bit);
        int lc = 0;
        #pragma unroll
        for (int j=0;j<64;++j) lc += (kk[j] >= cand) ? 1 : 0;
        #pragma unroll
        for (int off=1; off<64; off<<=1) lc += __shfl_xor(lc, off, 64);
        if (lc >= 64) Te = cand;
      }
      int b2 = 0;
      #pragma unroll
      for (int j=0;j<64;++j){
        unsigned u = kk[j];
        unsigned long long mg = __ballot(u > Te);
        if (u > Te){
          int slot = b2 + (int)__popcll(mg & below);
          if (slot < 64) candI[(w<<6)+slot] = ((j>>5)<<11)+((j&31)<<6)+lane;
        }
        b2 += (int)__popcll(mg);
      }
      #pragma unroll
      for (int j=0;j<64;++j){
        unsigned u = kk[j];
        unsigned long long mt2 = __ballot(u == Te);
        if (u == Te){
          int slot = b2 + (int)__popcll(mt2 & below);
          if (slot < 64) candI[(w<<6)+slot] = ((j>>5)<<11)+((j&31)<<6)+lane;
        }
        b2 += (int)__popcll(mt2);
      }
      S = 64;
    }
    __threadfence_block();
    // ---- EXACT fp32 rescore (identical fmaf chain as the all-VALU version)
    unsigned long long C = 0ull;
    if (lane < S){
      int mj = candI[(w<<6)+lane] & (Ndim-1);
      float a0 = 0.f;
      const float* xmp = xb + mj;
      #pragma unroll 8
      for (int c=0;c<64;++c) a0 = fmaf(fnS[(w<<6)+c], xmp[(size_t)c*Ndim], a0);
      float d = (2.f*a0 - sqnS[w]) - sq[b*Ndim + mj];
      C = ((unsigned long long)keyOf(d) << 32) | (unsigned long long)(~(unsigned)mj);
    }
    // bitonic sort 64 lanes desc (key, ~idx) -> stable top_k order
    #pragma unroll
    for (int k2=2; k2<=64; k2<<=1){
      #pragma unroll
      for (int j2=k2>>1; j2>=1; j2>>=1){
        unsigned long long P = (unsigned long long)__shfl_xor((long long)C, j2, 64);
        bool lowIdx  = ((lane & j2) == 0);
        bool keepMax = (lowIdx == ((lane & k2) == 0));
        unsigned long long mx = C > P ? C : P;
        unsigned long long mn = C > P ? P : C;
        C = keepMax ? mx : mn;
      }
    }
    if (lane < 32) outIdx[(w<<5)+lane] = (int)(~(unsigned)(C & 0xFFFFFFFFull)) & (Ndim-1);
  }
  __syncthreads();

  // ---- attention energies: 1024 tasks = 8q x 4h x 32k
  #pragma unroll
  for (int p=0;p<2;++p){
    int task = tid + (p<<9);
    int jn = task>>7, h = (task>>5)&3, k2 = task&31;
    int mj = outIdx[(jn<<5)+k2] & (Ndim-1);
    const float4* pk4 = (const float4*)(PKm + ((size_t)b*Ndim + mj)*64 + (h<<4));
    const float4* qq4 = (const float4*)&qvS[(jn<<6)+(h<<4)];
    const float4* nn4 = (const float4*)&pknS[(jn<<6)+(h<<4)];
    float e = 0.f;
    #pragma unroll
    for (int d=0;d<4;++d){
      float4 kv = pk4[d], qq = qq4[d], nn = nn4[d];
      e += qq.x*(kv.x-nn.x) + qq.y*(kv.y-nn.y) + qq.z*(kv.z-nn.z) + qq.w*(kv.w-nn.w);
    }
    enS[(jn<<7)+(h<<5)+k2] = e * 0.25f;
  }
  __syncthreads();
  if (tid < 32){
    int jn = tid>>2, h = tid&3;
    float* ep = &enS[(jn<<7)+(h<<5)];
    float mx = -1e30f;
    for (int k2=0;k2<32;++k2) mx = fmaxf(mx, ep[k2]);
    float ssum = 0.f;
    for (int k2=0;k2<32;++k2){ float ex = expf(ep[k2]-mx); ep[k2] = ex; ssum += ex; }
    float inv = 1.f/ssum;
    for (int k2=0;k2<32;++k2) ep[k2] *= inv;
  }
  __syncthreads();
  float tval;
  {
    int jn = tid>>6, c = tid&63, h = c>>4;
    float a2 = 0.f;
    #pragma unroll 8
    for (int k2=0;k2<32;++k2){
      int mj = outIdx[(jn<<5)+k2] & (Ndim-1);
      a2 += enS[(jn<<7)+(h<<5)+k2] * (PVm[((size_t)b*Ndim + mj)*64 + c] - pvnS[(jn<<6)+c]);
    }
    tval = fnS[(jn<<6)+c] + a2;
    t1[((size_t)b*Ndim + n0 + jn)*64 + c] = tval;
  }
  // ---- fused BN1 stats
  __syncthreads();
  red1[tid] = tval;
  red2[tid] = tval*tval;
  __syncthreads();
  if (tid < 64){
    float S = 0.f, S2 = 0.f;
    #pragma unroll
    for (int j=0;j<8;++j){ S += red1[(j<<6)+tid]; S2 += red2[(j<<6)+tid]; }
    atomicAdd(&bn1s[tid], S);
    atomicAdd(&bn1q[tid], S2);
  }
}

// ---------------------------------------------------------------- MLP + BN2 stats
__global__ __launch_bounds__(256) void mlp_kernel(const float* __restrict__ t1,
    const float* __restrict__ w1, const float* __restrict__ w2,
    const float* __restrict__ g1, const float* __restrict__ b1,
    const float* __restrict__ bns, const float* __restrict__ bnq,
    float* __restrict__ t2, float* __restrict__ bn2s, float* __restrict__ bn2q)
{
  __shared__ __align__(16) float f1l[64*68];
  __shared__ __align__(16) float hl[64*68];
  __shared__ __align__(16) float w1s[64*64];
  __shared__ __align__(16) float w2s[64*64];
  __shared__ float mu[64], rs[64], gg[64], bb[64];
  const int tid = threadIdx.x;
  if (tid < 64){
    float m = bns[tid] * (1.f/32768.f);
    float v = bnq[tid] * (1.f/32768.f) - m*m;
    mu[tid] = m; rs[tid] = 1.f/sqrtf(v + BN_EPS);
    gg[tid] = g1[tid]; bb[tid] = b1[tid];
  }
  __syncthreads();
  const size_t rowBase = (size_t)blockIdx.x*64;
  for (int k=0;k<16;++k){
    int idx = tid + (k<<8);
    int r = idx>>6, c = idx&63;
    float v = t1[(rowBase + r)*64 + c];
    f1l[r*68+c] = (v - mu[c])*rs[c]*gg[c] + bb[c];
  }
  const int tr = tid>>4, to = tid&15;
  float ff[4][4];
  #pragma unroll
  for (int r=0;r<4;++r){ ff[r][0]=0.f; ff[r][1]=0.f; ff[r][2]=0.f; ff[r][3]=0.f; }

  for (int hc=0; hc<4; ++hc){
    __syncthreads();
    for (int k=0;k<16;++k){
      int idx = tid + (k<<8);
      int o = idx>>6, c = idx&63;
      w1s[wofs(o, c>>2) + (c&3)] = w1[(size_t)(hc*64+o)*64 + c];
      w2s[wofs(o, c>>2) + (c&3)] = w2[(size_t)o*256 + hc*64 + c];
    }
    __syncthreads();
    float hv[4][4];
    #pragma unroll
    for (int r=0;r<4;++r){ hv[r][0]=0.f; hv[r][1]=0.f; hv[r][2]=0.f; hv[r][3]=0.f; }
    #pragma unroll 4
    for (int c4=0;c4<16;++c4){
      float4 f[4], w[4];
      #pragma unroll
      for (int r=0;r<4;++r)  f[r] = *(const float4*)&f1l[(4*tr+r)*68 + (c4<<2)];
      #pragma unroll
      for (int oo=0;oo<4;++oo) w[oo] = *(const float4*)&w1s[wofs(4*to+oo, c4)];
      #pragma unroll
      for (int r=0;r<4;++r)
        #pragma unroll
        for (int oo=0;oo<4;++oo)
          hv[r][oo] += dot4(f[r], w[oo]);
    }
    #pragma unroll
    for (int r=0;r<4;++r){
      float4 v;
      float x0=hv[r][0], x1=hv[r][1], x2=hv[r][2], x3=hv[r][3];
      v.x = (x0>0.f)?x0:0.2f*x0; v.y = (x1>0.f)?x1:0.2f*x1;
      v.z = (x2>0.f)?x2:0.2f*x2; v.w = (x3>0.f)?x3:0.2f*x3;
      *(float4*)&hl[(4*tr+r)*68 + 4*to] = v;
    }
    __syncthreads();
    #pragma unroll 4
    for (int o4=0;o4<16;++o4){
      float4 h[4], w[4];
      #pragma unroll
      for (int r=0;r<4;++r)  h[r] = *(const float4*)&hl[(4*tr+r)*68 + (o4<<2)];
      #pragma unroll
      for (int oo=0;oo<4;++oo) w[oo] = *(const float4*)&w2s[wofs(4*to+oo, o4)];
      #pragma unroll
      for (int r=0;r<4;++r)
        #pragma unroll
        for (int oo=0;oo<4;++oo)
          ff[r][oo] += dot4(h[r], w[oo]);
    }
  }
  float ls[4]  = {0.f,0.f,0.f,0.f};
  float ls2[4] = {0.f,0.f,0.f,0.f};
  #pragma unroll
  for (int r=0;r<4;++r){
    float4 v;
    v.x = f1l[(4*tr+r)*68 + 4*to+0] + ff[r][0];
    v.y = f1l[(4*tr+r)*68 + 4*to+1] + ff[r][1];
    v.z = f1l[(4*tr+r)*68 + 4*to+2] + ff[r][2];
    v.w = f1l[(4*tr+r)*68 + 4*to+3] + ff[r][3];
    *(float4*)&t2[(rowBase + 4*tr + r)*64 + 4*to] = v;
    ls[0]+=v.x; ls[1]+=v.y; ls[2]+=v.z; ls[3]+=v.w;
    ls2[0]+=v.x*v.x; ls2[1]+=v.y*v.y; ls2[2]+=v.z*v.z; ls2[3]+=v.w*v.w;
  }
  __syncthreads();
  #pragma unroll
  for (int i=0;i<4;++i){
    hl[tr*64 + 4*to + i]        = ls[i];
    hl[1024 + tr*64 + 4*to + i] = ls2[i];
  }
  __syncthreads();
  if (tid < 64){
    float S = 0.f, S2 = 0.f;
    #pragma unroll
    for (int g2=0; g2<16; ++g2){ S += hl[g2*64 + tid]; S2 += hl[1024 + g2*64 + tid]; }
    atomicAdd(&bn2s[tid], S);
    atomicAdd(&bn2q[tid], S2);
  }
}

// ---------------------------------------------------------------- final BN2 + transpose
__global__ __launch_bounds__(256) void final_kernel(const float* __restrict__ t2,
    const float* __restrict__ bns, const float* __restrict__ bnq,
    const float* __restrict__ g2, const float* __restrict__ b2,
    float* __restrict__ out)
{
  __shared__ float tile[64*65];
  __shared__ float mu[64], rs[64], gg[64], bb[64];
  const int tid = threadIdx.x;
  const int b = blockIdx.y;
  const int n0 = blockIdx.x*64;
  if (tid < 64){
    float m = bns[tid] * (1.f/32768.f);
    float v = bnq[tid] * (1.f/32768.f) - m*m;
    mu[tid] = m; rs[tid] = 1.f/sqrtf(v + BN_EPS);
    gg[tid] = g2[tid]; bb[tid] = b2[tid];
  }
  __syncthreads();
  for (int k=0;k<16;++k){
    int idx = tid + (k<<8);
    int r = idx>>6, c = idx&63;
    float v = t2[((size_t)b*Ndim + n0 + r)*64 + c];
    tile[r*65+c] = (v - mu[c])*rs[c]*gg[c] + bb[c];
  }
  __syncthreads();
  for (int k=0;k<16;++k){
    int idx = tid + (k<<8);
    int c = idx>>6, nn = idx&63;
    out[((size_t)b*64 + c)*Ndim + n0 + nn] = tile[nn*65+c];
  }
}

extern "C" void kernel_launch(void* const* d_in, const int* in_sizes, int n_in,
                              void* d_out, int out_size, void* d_ws, size_t ws_size,
                              hipStream_t stream)
{
  (void)in_sizes; (void)n_in; (void)out_size; (void)ws_size;
  const float* x  = (const float*)d_in[0];
  const float* wq = (const float*)d_in[1];
  const float* wk = (const float*)d_in[2];
  const float* wv = (const float*)d_in[3];
  const float* w1 = (const float*)d_in[4];
  const float* w2 = (const float*)d_in[5];
  const float* g1 = (const float*)d_in[6];
  const float* b1 = (const float*)d_in[7];
  const float* g2 = (const float*)d_in[8];
  const float* b2 = (const float*)d_in[9];
  float* out = (float*)d_out;

  const size_t NE = (size_t)ROWS*64;
  float* sq   = (float*)d_ws;
  float* Qb   = sq + ROWS;
  float* PKb  = Qb + NE;
  float* PVb  = PKb + NE;
  float* t1   = PVb + NE;
  float* t2   = t1 + NE;
  float* acc  = t2 + NE;   // 256 floats
  // P (bf16 hi/lo pack, 8 MB total) aliases t2: dead until mlp writes t2.
  short* Ph = (short*)t2;
  short* Pl = Ph + (size_t)2097152;

  prep_proj_kernel<<<dim3(512), 256, 0, stream>>>(x, wq, wk, wv, sq, Qb, PKb, PVb, acc, Ph, Pl);
  knn_attn_kernel<<<dim3(4096), 512, 0, stream>>>(x, sq, Qb, PKb, PVb, Ph, Pl, t1, acc, acc+64);
  mlp_kernel<<<dim3(512), 256, 0, stream>>>(t1, w1, w2, g1, b1, acc, acc+64, t2, acc+128, acc+192);
  final_kernel<<<dim3(64,8), 256, 0, stream>>>(t2, acc+128, acc+192, g2, b2, out);
}